// Round 1
// baseline (825.524 us; speedup 1.0000x reference)
//
#include <hip/hip_runtime.h>

#define N 512
#define WAVES 16
#define BLOCK (WAVES * 64)          // 1024 threads, 16 waves
#define ROWS_PER_WAVE (N / WAVES)   // 32

// Sinkhorn in "materialized exp" form. With E = exp(a):
//   row pass:  S_i = sum_j E_ij * wv_j   (wv_j = exp(-v_j) = 1/t_j)
//   col pass:  t_j = sum_i E_ij / S_i
//   output:    exp(a - u - v) = E_ij * (1/S_i) * (1/t_j)
// => exp() is evaluated exactly ONCE per element (pass 0); all subsequent
// passes are pure FMA streaming, and log() is never needed at all.
// E lives in Out (scratch until the final sweep overwrites it in place).
// Each wave re-reads only the rows it wrote, so no cross-wave global
// coherence is needed beyond the existing __syncthreads (vmcnt drain).
__global__ __launch_bounds__(BLOCK, 1)
void sinkhorn_kernel(const float* __restrict__ A, float* __restrict__ Out) {
    __shared__ float swv[N];            // 1/t_j = exp(-v_j)
    __shared__ float sinvS[N];          // 1/S_i from the latest row pass
    __shared__ float spart[WAVES][N];   // per-wave column-sum partials (32 KiB)

    const float* __restrict__ Ab = A   + (size_t)blockIdx.x * N * N;
    float* __restrict__ Eb       = Out + (size_t)blockIdx.x * N * N;
    const int tid  = threadIdx.x;
    const int lane = tid & 63;
    const int wave = tid >> 6;

    // ---------------- pass 0: E = exp(a) (v = 0), S_i, t partials ----------
    {
        float t0=0.f,t1=0.f,t2=0.f,t3=0.f,t4=0.f,t5=0.f,t6=0.f,t7=0.f;
        #pragma unroll 4
        for (int k = 0; k < ROWS_PER_WAVE; ++k) {
            const int row = k * WAVES + wave;   // waves sweep a moving 32KiB window
            const float4* R = (const float4*)(Ab + (size_t)row * N);
            float4*       W = (float4*)(Eb + (size_t)row * N);
            const float4 x0 = R[lane];
            const float4 x1 = R[lane + 64];

            const float e0 = __expf(x0.x), e1 = __expf(x0.y),
                        e2 = __expf(x0.z), e3 = __expf(x0.w);
            const float e4 = __expf(x1.x), e5 = __expf(x1.y),
                        e6 = __expf(x1.z), e7 = __expf(x1.w);

            W[lane]      = make_float4(e0, e1, e2, e3);
            W[lane + 64] = make_float4(e4, e5, e6, e7);

            float S = ((e0 + e1) + (e2 + e3)) + ((e4 + e5) + (e6 + e7));
            #pragma unroll
            for (int m = 1; m < 64; m <<= 1) S += __shfl_xor(S, m, 64);

            const float inv = 1.0f / S;
            if (lane == 0) sinvS[row] = inv;

            t0 += e0 * inv; t1 += e1 * inv; t2 += e2 * inv; t3 += e3 * inv;
            t4 += e4 * inv; t5 += e5 * inv; t6 += e6 * inv; t7 += e7 * inv;
        }
        ((float4*)spart[wave])[lane]      = make_float4(t0, t1, t2, t3);
        ((float4*)spart[wave])[lane + 64] = make_float4(t4, t5, t6, t7);
        __syncthreads();
        if (tid < N) {
            float s = 0.f;
            #pragma unroll
            for (int w = 0; w < WAVES; ++w) s += spart[w][tid];
            swv[tid] = 1.0f / s;            // exp(-v_j)
        }
        __syncthreads();
    }

    // ---------------- passes 1..9: pure-FMA streaming sweeps ---------------
    for (int pass = 1; pass < 10; ++pass) {
        const float4 w0 = ((const float4*)swv)[lane];
        const float4 w1 = ((const float4*)swv)[lane + 64];
        float t0=0.f,t1=0.f,t2=0.f,t3=0.f,t4=0.f,t5=0.f,t6=0.f,t7=0.f;

        #pragma unroll 4
        for (int k = 0; k < ROWS_PER_WAVE; ++k) {
            const int row = k * WAVES + wave;
            const float4* R = (const float4*)(Eb + (size_t)row * N);
            const float4 a0 = R[lane];
            const float4 a1 = R[lane + 64];

            const float s01 = a0.x * w0.x + a0.y * w0.y;
            const float s23 = a0.z * w0.z + a0.w * w0.w;
            const float s45 = a1.x * w1.x + a1.y * w1.y;
            const float s67 = a1.z * w1.z + a1.w * w1.w;
            float S = (s01 + s23) + (s45 + s67);
            #pragma unroll
            for (int m = 1; m < 64; m <<= 1) S += __shfl_xor(S, m, 64);

            const float inv = 1.0f / S;
            if (lane == 0) sinvS[row] = inv;

            t0 += a0.x * inv; t1 += a0.y * inv; t2 += a0.z * inv; t3 += a0.w * inv;
            t4 += a1.x * inv; t5 += a1.y * inv; t6 += a1.z * inv; t7 += a1.w * inv;
        }

        ((float4*)spart[wave])[lane]      = make_float4(t0, t1, t2, t3);
        ((float4*)spart[wave])[lane + 64] = make_float4(t4, t5, t6, t7);
        __syncthreads();
        if (tid < N) {
            float s = 0.f;
            #pragma unroll
            for (int w = 0; w < WAVES; ++w) s += spart[w][tid];
            swv[tid] = 1.0f / s;
        }
        __syncthreads();
    }

    // ---------------- output: out = E * (1/S_i) * (1/t_j), in place --------
    {
        const float4 w0 = ((const float4*)swv)[lane];
        const float4 w1 = ((const float4*)swv)[lane + 64];
        #pragma unroll 4
        for (int k = 0; k < ROWS_PER_WAVE; ++k) {
            const int row = k * WAVES + wave;
            float4* W = (float4*)(Eb + (size_t)row * N);
            const float4 a0 = W[lane];
            const float4 a1 = W[lane + 64];
            const float c = sinvS[row];

            float4 o0, o1;
            o0.x = a0.x * (c * w0.x);
            o0.y = a0.y * (c * w0.y);
            o0.z = a0.z * (c * w0.z);
            o0.w = a0.w * (c * w0.w);
            o1.x = a1.x * (c * w1.x);
            o1.y = a1.y * (c * w1.y);
            o1.z = a1.z * (c * w1.z);
            o1.w = a1.w * (c * w1.w);

            W[lane]      = o0;
            W[lane + 64] = o1;
        }
    }
}

extern "C" void kernel_launch(void* const* d_in, const int* in_sizes, int n_in,
                              void* d_out, int out_size, void* d_ws, size_t ws_size,
                              hipStream_t stream) {
    const float* s = (const float*)d_in[0];
    float* out = (float*)d_out;
    const int nmat = in_sizes[0] / (N * N);   // 256
    sinkhorn_kernel<<<nmat, BLOCK, 0, stream>>>(s, out);
}

// Round 2
// 751.342 us; speedup vs baseline: 1.0987x; 1.0987x over previous
//
#include <hip/hip_runtime.h>
#include <hip/hip_fp16.h>

#define N 512
#define WAVES 16
#define BLOCK (WAVES * 64)          // 1024 threads, 16 waves
#define ROWS_PER_WAVE (N / WAVES)   // 32

// Sinkhorn, materialized-exp form with fp16 E.
//   E = exp(a)  stored ONCE as fp16 (128 MB total -> L3-resident working set)
//   row pass:  S_i = sum_j E_ij * wv_j     (wv_j = exp(-v_j) = 1/t_j)
//   col pass:  t_j = sum_i E_ij / S_i
//   output:    out = exp(a) * (1/S_i) * (1/t_j)   <- recomputed from fp32 A,
//              so E's fp16 quantization never touches the output directly;
//              it only perturbs the normalizers via averaged sums (~2e-5 rel).
// E lives in the first 512 KiB of each matrix's Out region. It is dead before
// the output pass writes fp32 over it (same block, after the pass-9 barrier).
// Each wave only ever re-reads E rows it wrote itself (row = k*WAVES + wave).
__global__ __launch_bounds__(BLOCK, 1)
void sinkhorn_kernel(const float* __restrict__ A, float* __restrict__ Out) {
    __shared__ float swv[N];            // 1/t_j = exp(-v_j)
    __shared__ float sinvS[N];          // 1/S_i from the latest row pass
    __shared__ float spart[WAVES][N];   // per-wave column-sum partials (32 KiB)

    const float* __restrict__ Ab = A   + (size_t)blockIdx.x * (N * N);
    float* __restrict__ Ob       = Out + (size_t)blockIdx.x * (N * N);
    __half* __restrict__ Eh      = (__half*)Ob;   // fp16 scratch

    const int tid  = threadIdx.x;
    const int lane = tid & 63;
    const int wave = tid >> 6;

    // ---------------- pass 0: E = exp(a) -> fp16; S_i; col partials --------
    // Lane owns columns 8L..8L+7 (two strided float4 A-loads; full row is
    // fetched once, second load hits L1).
    {
        float t0=0.f,t1=0.f,t2=0.f,t3=0.f,t4=0.f,t5=0.f,t6=0.f,t7=0.f;
        #pragma unroll 4
        for (int k = 0; k < ROWS_PER_WAVE; ++k) {
            const int row = k * WAVES + wave;
            const float4* R = (const float4*)(Ab + (size_t)row * N);
            const float4 x0 = R[2 * lane];
            const float4 x1 = R[2 * lane + 1];

            const float e0 = __expf(x0.x), e1 = __expf(x0.y),
                        e2 = __expf(x0.z), e3 = __expf(x0.w);
            const float e4 = __expf(x1.x), e5 = __expf(x1.y),
                        e6 = __expf(x1.z), e7 = __expf(x1.w);

            float4 pk;
            ((__half2*)&pk)[0] = __floats2half2_rn(e0, e1);
            ((__half2*)&pk)[1] = __floats2half2_rn(e2, e3);
            ((__half2*)&pk)[2] = __floats2half2_rn(e4, e5);
            ((__half2*)&pk)[3] = __floats2half2_rn(e6, e7);
            ((float4*)(Eh + (size_t)row * N))[lane] = pk;   // 16B = 8 halves

            float S = ((e0 + e1) + (e2 + e3)) + ((e4 + e5) + (e6 + e7));
            #pragma unroll
            for (int m = 1; m < 64; m <<= 1) S += __shfl_xor(S, m, 64);

            const float inv = 1.0f / S;
            if (lane == 0) sinvS[row] = inv;

            t0 += e0 * inv; t1 += e1 * inv; t2 += e2 * inv; t3 += e3 * inv;
            t4 += e4 * inv; t5 += e5 * inv; t6 += e6 * inv; t7 += e7 * inv;
        }
        ((float4*)spart[wave])[2 * lane]     = make_float4(t0, t1, t2, t3);
        ((float4*)spart[wave])[2 * lane + 1] = make_float4(t4, t5, t6, t7);
        __syncthreads();
        if (tid < N) {
            float s = 0.f;
            #pragma unroll
            for (int w = 0; w < WAVES; ++w) s += spart[w][tid];
            swv[tid] = 1.0f / s;            // exp(-v_j)
        }
        __syncthreads();
    }

    // ---------------- passes 1..9: fp16 streaming sweeps (L3-resident) -----
    for (int pass = 1; pass < 10; ++pass) {
        const float4 wa = ((const float4*)swv)[2 * lane];      // cols 8L..8L+3
        const float4 wb = ((const float4*)swv)[2 * lane + 1];  // cols 8L+4..8L+7
        float t0=0.f,t1=0.f,t2=0.f,t3=0.f,t4=0.f,t5=0.f,t6=0.f,t7=0.f;

        #pragma unroll 8
        for (int k = 0; k < ROWS_PER_WAVE; ++k) {
            const int row = k * WAVES + wave;
            const float4 raw = ((const float4*)(Eh + (size_t)row * N))[lane];
            const __half2* h = (const __half2*)&raw;
            const float2 f01 = __half22float2(h[0]);
            const float2 f23 = __half22float2(h[1]);
            const float2 f45 = __half22float2(h[2]);
            const float2 f67 = __half22float2(h[3]);

            const float s01 = f01.x * wa.x + f01.y * wa.y;
            const float s23 = f23.x * wa.z + f23.y * wa.w;
            const float s45 = f45.x * wb.x + f45.y * wb.y;
            const float s67 = f67.x * wb.z + f67.y * wb.w;
            float S = (s01 + s23) + (s45 + s67);
            #pragma unroll
            for (int m = 1; m < 64; m <<= 1) S += __shfl_xor(S, m, 64);

            const float inv = 1.0f / S;
            if (lane == 0) sinvS[row] = inv;

            t0 += f01.x * inv; t1 += f01.y * inv;
            t2 += f23.x * inv; t3 += f23.y * inv;
            t4 += f45.x * inv; t5 += f45.y * inv;
            t6 += f67.x * inv; t7 += f67.y * inv;
        }

        ((float4*)spart[wave])[2 * lane]     = make_float4(t0, t1, t2, t3);
        ((float4*)spart[wave])[2 * lane + 1] = make_float4(t4, t5, t6, t7);
        __syncthreads();
        if (tid < N) {
            float s = 0.f;
            #pragma unroll
            for (int w = 0; w < WAVES; ++w) s += spart[w][tid];
            swv[tid] = 1.0f / s;
        }
        __syncthreads();
    }

    // ------- output: out = exp(a) * (1/S_i) * (1/t_j), from fp32 A ---------
    // Dense layout (cols 4L.. and 256+4L..) for fully-dense stores. E (first
    // 512 KiB of Ob) is dead now; overwriting it is safe within this block.
    {
        const float4 w0 = ((const float4*)swv)[lane];
        const float4 w1 = ((const float4*)swv)[lane + 64];
        #pragma unroll 4
        for (int k = 0; k < ROWS_PER_WAVE; ++k) {
            const int row = k * WAVES + wave;
            const float4* R = (const float4*)(Ab + (size_t)row * N);
            float4*       W = (float4*)(Ob + (size_t)row * N);
            const float4 x0 = R[lane];
            const float4 x1 = R[lane + 64];
            const float c = sinvS[row];

            float4 o0, o1;
            o0.x = __expf(x0.x) * (c * w0.x);
            o0.y = __expf(x0.y) * (c * w0.y);
            o0.z = __expf(x0.z) * (c * w0.z);
            o0.w = __expf(x0.w) * (c * w0.w);
            o1.x = __expf(x1.x) * (c * w1.x);
            o1.y = __expf(x1.y) * (c * w1.y);
            o1.z = __expf(x1.z) * (c * w1.z);
            o1.w = __expf(x1.w) * (c * w1.w);

            W[lane]      = o0;
            W[lane + 64] = o1;
        }
    }
}

extern "C" void kernel_launch(void* const* d_in, const int* in_sizes, int n_in,
                              void* d_out, int out_size, void* d_ws, size_t ws_size,
                              hipStream_t stream) {
    const float* s = (const float*)d_in[0];
    float* out = (float*)d_out;
    const int nmat = in_sizes[0] / (N * N);   // 256
    sinkhorn_kernel<<<nmat, BLOCK, 0, stream>>>(s, out);
}